// Round 7
// baseline (31.825 us; speedup 1.0000x reference)
//
#include <hip/hip_runtime.h>

#define NBATCH 256
#define NJ     62
#define NV     14522
#define NCORE  28
#define KPAD   256    // 62*4 = 248 padded to 256 (512 B per row)
#define NN     768
#define MPAD   14528
#define OUTF   (NV * 3)        // 43566
#define MT     908             // m-tiles of 16 rows
#define NSTRIPE 128            // stripes; tiles = s + 128*t

typedef __attribute__((ext_vector_type(8))) short short8v;
typedef __attribute__((ext_vector_type(4))) short short4v;
typedef __attribute__((ext_vector_type(4))) float floatx4;
typedef __attribute__((ext_vector_type(2))) float floatx2;

#define AS1(p) ((const __attribute__((address_space(1))) void*)(p))
#define AS3(p) ((__attribute__((address_space(3))) void*)(p))

#define SCHED0() __builtin_amdgcn_sched_barrier(0)
#define WAITVM(n) do { SCHED0(); asm volatile("s_waitcnt vmcnt(" #n ")" ::: "memory"); SCHED0(); } while (0)

static __device__ inline short f2bf(float x) {
    unsigned u = __float_as_uint(x);
    unsigned r = (u + 0x7fffu + ((u >> 16) & 1u)) >> 16;
    return (short)r;
}

// XOR swizzle over 512B rows: involution; applied to global SOURCE at staging
// and to LDS read addresses (both-sides rule).
static __device__ inline unsigned swz(unsigned off) {
    return off ^ (((off >> 9) & 7u) << 4);
}

// ---------------------------------------------------------------------------
// Kernel 1 (fused prep): blocks [0,64) = FK (4 batches/block, 1 per wave);
// blocks [64,..) = build WH[v][4k+j] = w[v,k]*h_v[j] (bf16).
// ---------------------------------------------------------------------------
__global__ __launch_bounds__(256) void prep_kernel(
    const float* __restrict__ thetas, const float* __restrict__ blc,
    const float* __restrict__ cbl, const float* __restrict__ trans,
    const float* __restrict__ scale, const float* __restrict__ tpose,
    const int* __restrict__ parents, const int* __restrict__ mapper,
    const float* __restrict__ W, const float* __restrict__ vt,
    short* __restrict__ Bt, short* __restrict__ WH,
    float* __restrict__ Jout)
{
    __shared__ float Asm[4][NJ][12];
    __shared__ float Gsm[4][NJ][12];

    if (blockIdx.x >= 64) {
        const int id = (blockIdx.x - 64) * 256 + threadIdx.x;
        const int v = id >> 5;
        const int c = id & 31;
        const int k = c * 2;
        float w0 = 0.f, w1 = 0.f, hx = 0.f, hy = 0.f, hz = 0.f;
        if (v < NV) {
            hx = vt[v * 3 + 0]; hy = vt[v * 3 + 1]; hz = vt[v * 3 + 2];
            if (k < NJ)     w0 = W[(size_t)v * NJ + k];
            if (k + 1 < NJ) w1 = W[(size_t)v * NJ + k + 1];
        }
        short8v o;
        o[0] = f2bf(w0 * hx); o[1] = f2bf(w0 * hy); o[2] = f2bf(w0 * hz); o[3] = f2bf(w0);
        o[4] = f2bf(w1 * hx); o[5] = f2bf(w1 * hy); o[6] = f2bf(w1 * hz); o[7] = f2bf(w1);
        if (v < MPAD) *(short8v*)&WH[(size_t)v * KPAD + c * 8] = o;
        return;
    }

    const int w = threadIdx.x >> 6;
    const int b = blockIdx.x * 4 + w;
    const int k = threadIdx.x & 63;
    int p = 0;

    if (k < NJ) {
        p = parents[k];
        const float tz = thetas[(b * NJ + k) * 3 + 0];
        const float ty = thetas[(b * NJ + k) * 3 + 1];
        const float tx = thetas[(b * NJ + k) * 3 + 2];
        const float cx = cosf(tx), sx = sinf(tx);
        const float cy = cosf(ty), sy = sinf(ty);
        const float cz = cosf(tz), sz = sinf(tz);
        const float r00 = cz * cy;
        const float r01 = cz * sy * sx - sz * cx;
        const float r02 = sz * sx + cz * sy * cx;
        const float r10 = sz * cy;
        const float r11 = cz * cx + sz * sy * sx;
        const float r12 = sz * sy * cx - cz * sx;
        const float r20 = -sy;
        const float r21 = cy * sx;
        const float r22 = cy * cx;

        float f;
        const int m = mapper[k];
        if (k == 0)        f = 1.0f;
        else if (k == 1)   f = cbl[b];
        else if (m < 0)    f = 1.0f;
        else               f = 2.0f / (1.0f + expf(-blc[b * NCORE + m] * 0.2f));

        float ox, oy, oz;
        if (k == 0) {
            ox = tpose[0]; oy = tpose[1]; oz = tpose[2];
        } else {
            ox = (tpose[k * 3 + 0] - tpose[p * 3 + 0]) * f;
            oy = (tpose[k * 3 + 1] - tpose[p * 3 + 1]) * f;
            oz = (tpose[k * 3 + 2] - tpose[p * 3 + 2]) * f;
        }
        Asm[w][k][0] = r00; Asm[w][k][1] = r01; Asm[w][k][2]  = r02; Asm[w][k][3]  = ox;
        Asm[w][k][4] = r10; Asm[w][k][5] = r11; Asm[w][k][6]  = r12; Asm[w][k][7]  = oy;
        Asm[w][k][8] = r20; Asm[w][k][9] = r21; Asm[w][k][10] = r22; Asm[w][k][11] = oz;
    }
    __syncthreads();

    if (k == 0) {
        #pragma unroll
        for (int j = 0; j < 12; ++j) Gsm[w][0][j] = Asm[w][0][j];
    }
    __syncthreads();

    const int depth = (k < NJ) ? (31 - __clz((unsigned)(k + 1))) : 99;
    for (int d = 1; d <= 5; ++d) {
        if (depth == d) {
            float gp[12], a[12], g[12];
            #pragma unroll
            for (int j = 0; j < 12; ++j) { gp[j] = Gsm[w][p][j]; a[j] = Asm[w][k][j]; }
            #pragma unroll
            for (int i = 0; i < 3; ++i) {
                #pragma unroll
                for (int j = 0; j < 4; ++j) {
                    float s = (j == 3) ? gp[i * 4 + 3] : 0.0f;
                    s = fmaf(gp[i * 4 + 0], a[0 * 4 + j], s);
                    s = fmaf(gp[i * 4 + 1], a[1 * 4 + j], s);
                    s = fmaf(gp[i * 4 + 2], a[2 * 4 + j], s);
                    g[i * 4 + j] = s;
                }
            }
            #pragma unroll
            for (int j = 0; j < 12; ++j) Gsm[w][k][j] = g[j];
        }
        __syncthreads();
    }

    if (k < NJ) {
        float g[12];
        #pragma unroll
        for (int j = 0; j < 12; ++j) g[j] = Gsm[w][k][j];
        const float jx = tpose[k * 3 + 0];
        const float jy = tpose[k * 3 + 1];
        const float jz = tpose[k * 3 + 2];
        const float s  = scale[b];
        Jout[(b * NJ + k) * 3 + 0] = fmaf(g[3],  s, trans[b * 3 + 0]);
        Jout[(b * NJ + k) * 3 + 1] = fmaf(g[7],  s, trans[b * 3 + 1]);
        Jout[(b * NJ + k) * 3 + 2] = fmaf(g[11], s, trans[b * 3 + 2]);
        float np[3];
        np[0] = g[3]  - (g[0] * jx + g[1] * jy + g[2]  * jz);
        np[1] = g[7]  - (g[4] * jx + g[5] * jy + g[6]  * jz);
        np[2] = g[11] - (g[8] * jx + g[9] * jy + g[10] * jz);
        #pragma unroll
        for (int i = 0; i < 3; ++i) {
            short4v o;
            o[0] = f2bf(g[i * 4 + 0]);
            o[1] = f2bf(g[i * 4 + 1]);
            o[2] = f2bf(g[i * 4 + 2]);
            o[3] = f2bf(np[i]);
            *(short4v*)&Bt[(size_t)(b * 3 + i) * KPAD + k * 4] = o;
        }
        if (k == 0) {
            short4v z = {0, 0, 0, 0};
            #pragma unroll
            for (int i = 0; i < 3; ++i) {
                *(short4v*)&Bt[(size_t)(b * 3 + i) * KPAD + 248] = z;
                *(short4v*)&Bt[(size_t)(b * 3 + i) * KPAD + 252] = z;
            }
        }
    }
}

// ---------------------------------------------------------------------------
// Kernel 2: GEMM + epilogue, A-tile shared block-wide.
// Grid 512 x 256 thr. Block: stripe s = bid&127, quad g = bid>>7.
// Wave w covers y-group (g*4+w) -> 16 batches; B-slab (48 x K) in 96 VGPR
// loaded once directly from global. Per m-tile (16 rows, = s+128t): one
// shared 8KB A DMA (double-buffered, 4 waves x 2 chunks), 1 barrier/tile,
// counted vmcnt(6) keeps stores in flight. A re-read traffic: 4x total
// (30 MB) instead of 16x, independent of XCD mapping.
// ---------------------------------------------------------------------------
__global__ __launch_bounds__(256, 2) void gemm_skin(
    const short* __restrict__ WH,     // (MPAD, KPAD) bf16
    const short* __restrict__ Bt,     // (NN, KPAD) bf16
    const float* __restrict__ scale,  // (B,)
    const float* __restrict__ trans,  // (B*3,)
    float* __restrict__ out)          // (B, V, 3)
{
    __shared__ __align__(16) char lds_raw[16384 + 4 * 3200];  // A dbuf + epi

    const int tid  = threadIdx.x;
    const int wave = tid >> 6;
    const int lane = tid & 63;
    const int lrow = lane & 15;
    const int lk   = lane >> 4;
    const int s    = blockIdx.x & 127;         // stripe
    const int g    = blockIdx.x >> 7;          // 0..3
    const int yg   = g * 4 + wave;             // y-group 0..15
    const int b0   = yg * 16;
    const int ntiles = (s < (MT - 7 * NSTRIPE)) ? 8 : 7;   // s<12 -> 8

    char* Ab0 = lds_raw;
    char* Ab1 = lds_raw + 8192;
    float* epi = (float*)(lds_raw + 16384) + wave * 800;   // 16 regions x 50 f

    // ---- B slab -> registers directly from global (L2-hot, loaded once)
    short8v breg[3][8];
    {
        const short* Bw = Bt + (size_t)yg * 48 * KPAD;
        #pragma unroll
        for (int nt = 0; nt < 3; ++nt)
            #pragma unroll
            for (int k8 = 0; k8 < 8; ++k8)
                breg[nt][k8] = *(const short8v*)(Bw + (nt * 16 + lrow) * KPAD
                                                 + (k8 * 4 + lk) * 8);
    }

    // ---- per-thread invariants
    float sv[3], tv[3]; int bl3[3], ii3[3];
    #pragma unroll
    for (int nt = 0; nt < 3; ++nt) {
        const int n_loc = nt * 16 + lrow;
        bl3[nt] = n_loc / 3; ii3[nt] = n_loc - bl3[nt] * 3;
        sv[nt] = scale[b0 + bl3[nt]];
        tv[nt] = trans[(b0 + bl3[nt]) * 3 + ii3[nt]];
    }
    size_t sbase[6]; int loff[6], jj[6];
    #pragma unroll
    for (int it = 0; it < 6; ++it) {
        const int idx = it * 64 + lane;
        const int r = idx / 24, j = idx - r * 24;   // region, float2 index
        sbase[it] = (size_t)(b0 + r) * OUTF + 2 * j;
        loff[it]  = r * 50 + 2 * j;
        jj[it]    = j;
    }

    const unsigned arb = lrow * 512, arx = (lrow & 7u) << 4;
    const char* Asrc = (const char*)WH + (size_t)s * 8192;

    // ---- prologue: A[0] (8 chunks, 2 per wave)
    #pragma unroll
    for (int c = 0; c < 2; ++c) {
        const unsigned Lb = (unsigned)(wave * 2 + c) * 1024;
        __builtin_amdgcn_global_load_lds(AS1(Asrc + swz(Lb + lane * 16)),
                                         AS3(Ab0 + Lb), 16, 0, 0);
    }
    WAITVM(0);
    __syncthreads();

    for (int t = 0; t < ntiles; ++t) {
        char* bufR = (t & 1) ? Ab1 : Ab0;

        // issue next shared A tile into the other buffer
        if (t + 1 < ntiles) {
            char* bufW = (t & 1) ? Ab0 : Ab1;
            const char* src = Asrc + (size_t)(t + 1) * (NSTRIPE * 8192);
            #pragma unroll
            for (int c = 0; c < 2; ++c) {
                const unsigned Lb = (unsigned)(wave * 2 + c) * 1024;
                __builtin_amdgcn_global_load_lds(AS1(src + swz(Lb + lane * 16)),
                                                 AS3(bufW + Lb), 16, 0, 0);
            }
        }

        // A frags (swizzled reads) + MFMA against register B
        short8v af[8];
        #pragma unroll
        for (int k8 = 0; k8 < 8; ++k8) {
            const unsigned cb = (unsigned)(k8 * 4 + lk) * 16;
            af[k8] = *(const short8v*)(bufR + arb + (cb ^ arx));
        }
        floatx4 acc[3];
        #pragma unroll
        for (int nt = 0; nt < 3; ++nt) acc[nt] = (floatx4){0.f, 0.f, 0.f, 0.f};
        #pragma unroll
        for (int k8 = 0; k8 < 8; ++k8) {
            #pragma unroll
            for (int nt = 0; nt < 3; ++nt)
                acc[nt] = __builtin_amdgcn_mfma_f32_16x16x32_bf16(
                    af[k8], breg[nt][k8], acc[nt], 0, 0, 0);
        }

        // epilogue transpose (wave-private region)
        #pragma unroll
        for (int nt = 0; nt < 3; ++nt) {
            #pragma unroll
            for (int r = 0; r < 4; ++r)
                epi[bl3[nt] * 50 + (lk * 4 + r) * 3 + ii3[nt]] =
                    fmaf(acc[nt][r], sv[nt], tv[nt]);
        }

        // coalesced stores: 16 regions x 24 float2
        const int m48 = (s + NSTRIPE * t) * 48;
        const bool edge = (m48 + 48 > OUTF);
        #pragma unroll
        for (int it = 0; it < 6; ++it) {
            const floatx2 val = *(const floatx2*)&epi[loff[it]];
            if (!edge || m48 + 2 * jj[it] + 1 < OUTF)
                *(floatx2*)&out[sbase[it] + m48] = val;
        }

        // wait own 2 A-chunks (oldest); the 6 stores stay in flight
        if (t + 1 < ntiles) {
            WAITVM(6);
            __syncthreads();   // all 8 chunks landed; all reads of bufR done
        }
    }
}

extern "C" void kernel_launch(void* const* d_in, const int* in_sizes, int n_in,
                              void* d_out, int out_size, void* d_ws, size_t ws_size,
                              hipStream_t stream)
{
    const float* thetas  = (const float*)d_in[0];
    const float* blc     = (const float*)d_in[1];
    const float* cbl     = (const float*)d_in[2];
    const float* trans   = (const float*)d_in[3];
    const float* scale   = (const float*)d_in[4];
    const float* vtempl  = (const float*)d_in[5];
    const float* tpose   = (const float*)d_in[6];
    const float* weights = (const float*)d_in[7];
    const int*   parents = (const int*)d_in[8];
    const int*   mapper  = (const int*)d_in[9];

    float* out  = (float*)d_out;
    float* Jout = out + (size_t)NBATCH * NV * 3;

    short* WH = (short*)d_ws;                          // MPAD*KPAD bf16 = 7.44 MB
    short* Bt = WH + (size_t)MPAD * KPAD;              // NN*KPAD bf16 = 0.39 MB

    prep_kernel<<<64 + (MPAD * 32) / 256, 256, 0, stream>>>(
        thetas, blc, cbl, trans, scale, tpose, parents, mapper,
        weights, vtempl, Bt, WH, Jout);
    gemm_skin<<<512, 256, 0, stream>>>(WH, Bt, scale, trans, out);
}

// Round 8
// 29.435 us; speedup vs baseline: 1.0812x; 1.0812x over previous
//
#include <hip/hip_runtime.h>

#define NBATCH 256
#define NJ     62
#define NV     14522
#define NCORE  28
#define KPAD   256    // 62*4 = 248 padded to 256 (512 B per row)
#define NN     768
#define MPAD   14528
#define OUTF   (NV * 3)        // 43566
#define MT     908             // m-tiles of 16 rows

typedef __attribute__((ext_vector_type(8))) short short8v;
typedef __attribute__((ext_vector_type(4))) short short4v;
typedef __attribute__((ext_vector_type(4))) float floatx4;
typedef __attribute__((ext_vector_type(2))) float floatx2;

#define AS1(p) ((const __attribute__((address_space(1))) void*)(p))
#define AS3(p) ((__attribute__((address_space(3))) void*)(p))

#define SCHED0() __builtin_amdgcn_sched_barrier(0)
#define WAITVM(n) do { SCHED0(); asm volatile("s_waitcnt vmcnt(" #n ")" ::: "memory"); SCHED0(); } while (0)

static __device__ inline short f2bf(float x) {
    unsigned u = __float_as_uint(x);
    unsigned r = (u + 0x7fffu + ((u >> 16) & 1u)) >> 16;
    return (short)r;
}

// XOR swizzle over 512B rows: involution; applied to global SOURCE at staging
// and to LDS read addresses (both-sides rule).
static __device__ inline unsigned swz(unsigned off) {
    return off ^ (((off >> 9) & 7u) << 4);
}

// ---------------------------------------------------------------------------
// Kernel 1 (fused prep): blocks [0,64) = FK (4 batches/block, 1 per wave);
// blocks [64,..) = build WH[v][4k+j] = w[v,k]*h_v[j] (bf16).
// ---------------------------------------------------------------------------
__global__ __launch_bounds__(256) void prep_kernel(
    const float* __restrict__ thetas, const float* __restrict__ blc,
    const float* __restrict__ cbl, const float* __restrict__ trans,
    const float* __restrict__ scale, const float* __restrict__ tpose,
    const int* __restrict__ parents, const int* __restrict__ mapper,
    const float* __restrict__ W, const float* __restrict__ vt,
    short* __restrict__ Bt, short* __restrict__ WH,
    float* __restrict__ Jout)
{
    __shared__ float Asm[4][NJ][12];
    __shared__ float Gsm[4][NJ][12];

    if (blockIdx.x >= 64) {
        const int id = (blockIdx.x - 64) * 256 + threadIdx.x;
        const int v = id >> 5;
        const int c = id & 31;
        const int k = c * 2;
        float w0 = 0.f, w1 = 0.f, hx = 0.f, hy = 0.f, hz = 0.f;
        if (v < NV) {
            hx = vt[v * 3 + 0]; hy = vt[v * 3 + 1]; hz = vt[v * 3 + 2];
            if (k < NJ)     w0 = W[(size_t)v * NJ + k];
            if (k + 1 < NJ) w1 = W[(size_t)v * NJ + k + 1];
        }
        short8v o;
        o[0] = f2bf(w0 * hx); o[1] = f2bf(w0 * hy); o[2] = f2bf(w0 * hz); o[3] = f2bf(w0);
        o[4] = f2bf(w1 * hx); o[5] = f2bf(w1 * hy); o[6] = f2bf(w1 * hz); o[7] = f2bf(w1);
        if (v < MPAD) *(short8v*)&WH[(size_t)v * KPAD + c * 8] = o;
        return;
    }

    const int w = threadIdx.x >> 6;
    const int b = blockIdx.x * 4 + w;
    const int k = threadIdx.x & 63;
    int p = 0;

    if (k < NJ) {
        p = parents[k];
        const float tz = thetas[(b * NJ + k) * 3 + 0];
        const float ty = thetas[(b * NJ + k) * 3 + 1];
        const float tx = thetas[(b * NJ + k) * 3 + 2];
        const float cx = cosf(tx), sx = sinf(tx);
        const float cy = cosf(ty), sy = sinf(ty);
        const float cz = cosf(tz), sz = sinf(tz);
        const float r00 = cz * cy;
        const float r01 = cz * sy * sx - sz * cx;
        const float r02 = sz * sx + cz * sy * cx;
        const float r10 = sz * cy;
        const float r11 = cz * cx + sz * sy * sx;
        const float r12 = sz * sy * cx - cz * sx;
        const float r20 = -sy;
        const float r21 = cy * sx;
        const float r22 = cy * cx;

        float f;
        const int m = mapper[k];
        if (k == 0)        f = 1.0f;
        else if (k == 1)   f = cbl[b];
        else if (m < 0)    f = 1.0f;
        else               f = 2.0f / (1.0f + expf(-blc[b * NCORE + m] * 0.2f));

        float ox, oy, oz;
        if (k == 0) {
            ox = tpose[0]; oy = tpose[1]; oz = tpose[2];
        } else {
            ox = (tpose[k * 3 + 0] - tpose[p * 3 + 0]) * f;
            oy = (tpose[k * 3 + 1] - tpose[p * 3 + 1]) * f;
            oz = (tpose[k * 3 + 2] - tpose[p * 3 + 2]) * f;
        }
        Asm[w][k][0] = r00; Asm[w][k][1] = r01; Asm[w][k][2]  = r02; Asm[w][k][3]  = ox;
        Asm[w][k][4] = r10; Asm[w][k][5] = r11; Asm[w][k][6]  = r12; Asm[w][k][7]  = oy;
        Asm[w][k][8] = r20; Asm[w][k][9] = r21; Asm[w][k][10] = r22; Asm[w][k][11] = oz;
    }
    __syncthreads();

    if (k == 0) {
        #pragma unroll
        for (int j = 0; j < 12; ++j) Gsm[w][0][j] = Asm[w][0][j];
    }
    __syncthreads();

    const int depth = (k < NJ) ? (31 - __clz((unsigned)(k + 1))) : 99;
    for (int d = 1; d <= 5; ++d) {
        if (depth == d) {
            float gp[12], a[12], g[12];
            #pragma unroll
            for (int j = 0; j < 12; ++j) { gp[j] = Gsm[w][p][j]; a[j] = Asm[w][k][j]; }
            #pragma unroll
            for (int i = 0; i < 3; ++i) {
                #pragma unroll
                for (int j = 0; j < 4; ++j) {
                    float s = (j == 3) ? gp[i * 4 + 3] : 0.0f;
                    s = fmaf(gp[i * 4 + 0], a[0 * 4 + j], s);
                    s = fmaf(gp[i * 4 + 1], a[1 * 4 + j], s);
                    s = fmaf(gp[i * 4 + 2], a[2 * 4 + j], s);
                    g[i * 4 + j] = s;
                }
            }
            #pragma unroll
            for (int j = 0; j < 12; ++j) Gsm[w][k][j] = g[j];
        }
        __syncthreads();
    }

    if (k < NJ) {
        float g[12];
        #pragma unroll
        for (int j = 0; j < 12; ++j) g[j] = Gsm[w][k][j];
        const float jx = tpose[k * 3 + 0];
        const float jy = tpose[k * 3 + 1];
        const float jz = tpose[k * 3 + 2];
        const float s  = scale[b];
        Jout[(b * NJ + k) * 3 + 0] = fmaf(g[3],  s, trans[b * 3 + 0]);
        Jout[(b * NJ + k) * 3 + 1] = fmaf(g[7],  s, trans[b * 3 + 1]);
        Jout[(b * NJ + k) * 3 + 2] = fmaf(g[11], s, trans[b * 3 + 2]);
        float np[3];
        np[0] = g[3]  - (g[0] * jx + g[1] * jy + g[2]  * jz);
        np[1] = g[7]  - (g[4] * jx + g[5] * jy + g[6]  * jz);
        np[2] = g[11] - (g[8] * jx + g[9] * jy + g[10] * jz);
        #pragma unroll
        for (int i = 0; i < 3; ++i) {
            short4v o;
            o[0] = f2bf(g[i * 4 + 0]);
            o[1] = f2bf(g[i * 4 + 1]);
            o[2] = f2bf(g[i * 4 + 2]);
            o[3] = f2bf(np[i]);
            *(short4v*)&Bt[(size_t)(b * 3 + i) * KPAD + k * 4] = o;
        }
        if (k == 0) {
            short4v z = {0, 0, 0, 0};
            #pragma unroll
            for (int i = 0; i < 3; ++i) {
                *(short4v*)&Bt[(size_t)(b * 3 + i) * KPAD + 248] = z;
                *(short4v*)&Bt[(size_t)(b * 3 + i) * KPAD + 252] = z;
            }
        }
    }
}

// ---------------------------------------------------------------------------
// Kernel 2: wave-autonomous GEMM + epilogue (r6 structure), CONTIGUOUS
// stripes: wave (bid,wid) handles y = bid>>5 (16 batches, B-slab in 96 VGPR)
// and m-tiles [start_s, start_s+ntiles), start_s = 7s+min(s,12),
// s = (bid&31)*4+wid. Consecutive tiles write consecutive 192B chunks of
// each batch-region -> L2 write-combining, no partial-line RMW (the r3
// counters showed ~25-30MB of RMW FETCH with strided stripes).
// Per tile: private 8KB A DMA (double-buffered, counted vmcnt, no barriers),
// 24 MFMA vs register B, wave-private LDS transpose, coalesced stores.
// ---------------------------------------------------------------------------
__global__ __launch_bounds__(256, 2) void gemm_skin(
    const short* __restrict__ WH,     // (MPAD, KPAD) bf16
    const short* __restrict__ Bt,     // (NN, KPAD) bf16
    const float* __restrict__ scale,  // (B,)
    const float* __restrict__ trans,  // (B*3,)
    float* __restrict__ out)          // (B, V, 3)
{
    __shared__ __align__(16) char lds_raw[65536 + 13312];  // A dbufs + epi

    const int tid  = threadIdx.x;
    const int wave = tid >> 6;
    const int lane = tid & 63;
    const int lrow = lane & 15;
    const int lk   = lane >> 4;
    const int y     = blockIdx.x >> 5;         // 0..15
    const int inner = blockIdx.x & 31;         // 0..31
    const int s     = inner * 4 + wave;        // stripe 0..127
    const int start  = s * 7 + (s < 12 ? s : 12);
    const int ntiles = 7 + (s < 12 ? 1 : 0);
    const int b0 = y * 16;

    char* Ab0 = lds_raw + wave * 16384;
    char* Ab1 = Ab0 + 8192;
    float* epi = (float*)(lds_raw + 65536) + wave * 800;   // 16 regions x 50 f

    // ---- stage B (24KB, overlays waves 0/1 A-dbufs transiently)
    {
        const char* Bsrc = (const char*)(Bt + (size_t)y * 48 * KPAD);
        #pragma unroll
        for (int cc = 0; cc < 6; ++cc) {
            const unsigned Lb = (unsigned)(wave * 6144 + cc * 1024);
            __builtin_amdgcn_global_load_lds(AS1(Bsrc + swz(Lb + lane * 16)),
                                             AS3(lds_raw + Lb), 16, 0, 0);
        }
    }
    WAITVM(0);
    __syncthreads();

    // ---- B slab -> registers (96 VGPR), swizzled reads
    short8v breg[3][8];
    #pragma unroll
    for (int nt = 0; nt < 3; ++nt) {
        const unsigned row = nt * 16 + lrow;
        const unsigned rb = row * 512, rx = (row & 7u) << 4;
        #pragma unroll
        for (int k8 = 0; k8 < 8; ++k8) {
            const unsigned cb = (unsigned)(k8 * 4 + lk) * 16;
            breg[nt][k8] = *(const short8v*)(lds_raw + rb + (cb ^ rx));
        }
    }
    __syncthreads();   // all waves done reading B before any A DMA overwrites

    // ---- per-thread invariants
    float sv[3], tv[3]; int bl3[3], ii3[3];
    #pragma unroll
    for (int nt = 0; nt < 3; ++nt) {
        const int n_loc = nt * 16 + lrow;
        bl3[nt] = n_loc / 3; ii3[nt] = n_loc - bl3[nt] * 3;
        sv[nt] = scale[b0 + bl3[nt]];
        tv[nt] = trans[(b0 + bl3[nt]) * 3 + ii3[nt]];
    }
    size_t sbase[6]; int loff[6], jj[6];
    #pragma unroll
    for (int it = 0; it < 6; ++it) {
        const int idx = it * 64 + lane;
        const int r = idx / 24, j = idx - r * 24;   // region, float2 index
        sbase[it] = (size_t)(b0 + r) * OUTF + 2 * j;
        loff[it]  = r * 50 + 2 * j;
        jj[it]    = j;
    }

    const unsigned arb = lrow * 512, arx = (lrow & 7u) << 4;
    const char* Asrc = (const char*)WH + (size_t)start * 8192;

    // ---- prologue: A[0]
    #pragma unroll
    for (int cc = 0; cc < 8; ++cc) {
        const unsigned Lb = cc * 1024;
        __builtin_amdgcn_global_load_lds(AS1(Asrc + swz(Lb + lane * 16)),
                                         AS3(Ab0 + Lb), 16, 0, 0);
    }
    WAITVM(0);

    for (int t = 0; t < ntiles; ++t) {
        char* bufR = (t & 1) ? Ab1 : Ab0;

        // issue next A tile (other buffer); its previous reads retired at t-1
        if (t + 1 < ntiles) {
            char* bufW = (t & 1) ? Ab0 : Ab1;
            const char* src = Asrc + (size_t)(t + 1) * 8192;
            #pragma unroll
            for (int cc = 0; cc < 8; ++cc) {
                const unsigned Lb = cc * 1024;
                __builtin_amdgcn_global_load_lds(AS1(src + swz(Lb + lane * 16)),
                                                 AS3(bufW + Lb), 16, 0, 0);
            }
        }

        // A frags (swizzled) + MFMA against register B
        short8v af[8];
        #pragma unroll
        for (int k8 = 0; k8 < 8; ++k8) {
            const unsigned cb = (unsigned)(k8 * 4 + lk) * 16;
            af[k8] = *(const short8v*)(bufR + arb + (cb ^ arx));
        }
        floatx4 acc[3];
        #pragma unroll
        for (int nt = 0; nt < 3; ++nt) acc[nt] = (floatx4){0.f, 0.f, 0.f, 0.f};
        #pragma unroll
        for (int k8 = 0; k8 < 8; ++k8) {
            #pragma unroll
            for (int nt = 0; nt < 3; ++nt)
                acc[nt] = __builtin_amdgcn_mfma_f32_16x16x32_bf16(
                    af[k8], breg[nt][k8], acc[nt], 0, 0, 0);
        }

        // epilogue transpose (wave-private region)
        #pragma unroll
        for (int nt = 0; nt < 3; ++nt) {
            #pragma unroll
            for (int r = 0; r < 4; ++r)
                epi[bl3[nt] * 50 + (lk * 4 + r) * 3 + ii3[nt]] =
                    fmaf(acc[nt][r], sv[nt], tv[nt]);
        }

        // coalesced stores: 16 regions x 24 float2 (consecutive chunks per
        // region across t -> L2 merges the misaligned 192B boundaries)
        const int m48 = (start + t) * 48;
        const bool edge = (m48 + 48 > OUTF);
        #pragma unroll
        for (int it = 0; it < 6; ++it) {
            const floatx2 val = *(const floatx2*)&epi[loff[it]];
            if (!edge || m48 + 2 * jj[it] + 1 < OUTF)
                *(floatx2*)&out[sbase[it] + m48] = val;
        }

        // A[t+1] landed; the 6 stores stay in flight
        if (t + 1 < ntiles) WAITVM(6);
    }
}

extern "C" void kernel_launch(void* const* d_in, const int* in_sizes, int n_in,
                              void* d_out, int out_size, void* d_ws, size_t ws_size,
                              hipStream_t stream)
{
    const float* thetas  = (const float*)d_in[0];
    const float* blc     = (const float*)d_in[1];
    const float* cbl     = (const float*)d_in[2];
    const float* trans   = (const float*)d_in[3];
    const float* scale   = (const float*)d_in[4];
    const float* vtempl  = (const float*)d_in[5];
    const float* tpose   = (const float*)d_in[6];
    const float* weights = (const float*)d_in[7];
    const int*   parents = (const int*)d_in[8];
    const int*   mapper  = (const int*)d_in[9];

    float* out  = (float*)d_out;
    float* Jout = out + (size_t)NBATCH * NV * 3;

    short* WH = (short*)d_ws;                          // MPAD*KPAD bf16 = 7.44 MB
    short* Bt = WH + (size_t)MPAD * KPAD;              // NN*KPAD bf16 = 0.39 MB

    prep_kernel<<<64 + (MPAD * 32) / 256, 256, 0, stream>>>(
        thetas, blc, cbl, trans, scale, tpose, parents, mapper,
        weights, vtempl, Bt, WH, Jout);
    gemm_skin<<<512, 256, 0, stream>>>(WH, Bt, scale, trans, out);
}